// Round 9
// baseline (8256.319 us; speedup 1.0000x reference)
//
#include <hip/hip_runtime.h>

#define B_ 32
#define S_ 512
#define H_ 1024
#define L_ 3
#define BH (B_*H_)     // 32768
#define NBLK 288       // 192 A-blocks (2 tiles each) + 96 B-blocks (2 tiles each)
#define PLANE 32768    // u16 elems in one A-frag-packed 32x1024 activation plane

typedef __attribute__((ext_vector_type(8))) short short8;
typedef __attribute__((ext_vector_type(4))) float f4;

__device__ __forceinline__ unsigned short f2bf(float f){
  unsigned int u = __float_as_uint(f);
  u += 0x7fffu + ((u >> 16) & 1u);   // RNE
  return (unsigned short)(u >> 16);
}
__device__ __forceinline__ float sigmoidf_(float x){
  return 1.0f / (1.0f + __expf(-x));
}
// offset (u16) of element (batch-row b, feature n) inside an A-frag-packed plane
// plane layout: [mh(2)][kb(32)][lane(64)][j(8)], lane = quad*16 + row
__device__ __forceinline__ int afrag_off(int b, int n){
  int mh = b >> 4, row = b & 15;
  int kb = n >> 5, quad = (n >> 3) & 3, j = n & 7;
  return (((mh * 32 + kb) * 64) + quad * 16 + row) * 8 + j;
}

// -------- device-coherent (agent scope) helpers -----------------------------
// Stores write through to the Infinity Cache; loads bypass stale L1/L2 and
// read IC. sc1 global_load_dwordx4 = agent-scope 16B load (half the IC
// transactions of 2x8B atomic loads). Hand-pipelined with counted vmcnt.
template<bool DC>
__device__ __forceinline__ short8 ldA(const unsigned short* p){
  short8 v;
  if constexpr (DC)
    asm volatile("global_load_dwordx4 %0, %1, off sc1" : "=&v"(v) : "v"(p));
  else
    asm volatile("global_load_dwordx4 %0, %1, off" : "=&v"(v) : "v"(p));
  return v;
}
template<int N>
__device__ __forceinline__ void waitv(){
  asm volatile("s_waitcnt vmcnt(%0)" :: "i"(N));
  __builtin_amdgcn_sched_barrier(0);   // rule #18: keep consumers below the wait
}
__device__ __forceinline__ float ldf_dc(const float* p){
  return __hip_atomic_load(p, __ATOMIC_RELAXED, __HIP_MEMORY_SCOPE_AGENT);
}
__device__ __forceinline__ void stf_dc(float* p, float v){
  __hip_atomic_store(p, v, __ATOMIC_RELAXED, __HIP_MEMORY_SCOPE_AGENT);
}
__device__ __forceinline__ void stu16_dc(unsigned short* p, unsigned short v){
  __hip_atomic_store(p, v, __ATOMIC_RELAXED, __HIP_MEMORY_SCOPE_AGENT);
}

// ---------------- prep: pack weights in MFMA-fragment order -----------------
__global__ void prep_WA_packed(const float* __restrict__ Wx, const float* __restrict__ Wz,
                               const float* __restrict__ Wr, const float* __restrict__ Wh,
                               unsigned short* __restrict__ WAp){
  int idx = blockIdx.x * blockDim.x + threadIdx.x;  // 384*64*64 exact
  int lane = idx & 63;
  int kb = (idx >> 6) & 63;
  int tile = idx >> 12;
  int g = tile >> 7, jt = tile & 127;
  int quad = lane >> 4, l15 = lane & 15;
  int n = jt * 16 + l15;
  int k0 = kb * 32 + quad * 8;
  int col = n & 1023;
  const float* W = (k0 < 1024) ? ((n < 1024) ? Wx : Wr) : ((n < 1024) ? Wz : Wh);
  const float* src = W + ((size_t)g * 1024 + (k0 & 1023)) * 1024 + col;
  short8 v;
  #pragma unroll
  for (int j = 0; j < 8; ++j) v[j] = (short)f2bf(src[(size_t)j * 1024]);
  *(short8*)(WAp + (size_t)idx * 8) = v;
}

__global__ void prep_WB_packed(const float* __restrict__ Wg, const float* __restrict__ Whg,
                               unsigned short* __restrict__ WBp){
  int idx = blockIdx.x * blockDim.x + threadIdx.x;  // 192*64*64 exact
  int lane = idx & 63;
  int kb = (idx >> 6) & 63;
  int tile = idx >> 12;
  int g = tile >> 6, jt = tile & 63;
  int quad = lane >> 4, l15 = lane & 15;
  int n = jt * 16 + l15;
  int k0 = kb * 32 + quad * 8;
  const float* W = (k0 < 1024) ? Wg : Whg;
  const float* src = W + ((size_t)g * 1024 + (k0 & 1023)) * 1024 + n;
  short8 v;
  #pragma unroll
  for (int j = 0; j < 8; ++j) v[j] = (short)f2bf(src[(size_t)j * 1024]);
  *(short8*)(WBp + (size_t)idx * 8) = v;
}

__global__ void prep_Wout_packed(const float* __restrict__ Wout,
                                 unsigned short* __restrict__ WoutP){
  int idx = blockIdx.x * blockDim.x + threadIdx.x;  // 64*32*64 exact
  int lane = idx & 63;
  int kb = (idx >> 6) & 31;
  int tile = idx >> 11;
  int quad = lane >> 4, l15 = lane & 15;
  int n = tile * 16 + l15;
  int k0 = kb * 32 + quad * 8;
  const float* src = Wout + (size_t)k0 * 1024 + n;
  short8 v;
  #pragma unroll
  for (int j = 0; j < 8; ++j) v[j] = (short)f2bf(src[(size_t)j * 1024]);
  *(short8*)(WoutP + (size_t)idx * 8) = v;
}

__global__ void prep_X_packed(const float* __restrict__ x, unsigned short* __restrict__ Xp){
  size_t idx = (size_t)blockIdx.x * blockDim.x + threadIdx.x;  // 512*32768 exact
  int j = (int)(idx & 7);
  int lane = (int)((idx >> 3) & 63);
  int kb = (int)((idx >> 9) & 31);
  int mh = (int)((idx >> 14) & 1);
  int t = (int)(idx >> 15);
  int b = mh * 16 + (lane & 15);
  int i = kb * 32 + (lane >> 4) * 8 + j;
  Xp[idx] = f2bf(x[((size_t)b * S_ + t) * 1024 + i]);
}

__global__ void prep_H0_kernel(const float* __restrict__ h0,
                               unsigned short* __restrict__ HTb, float* __restrict__ HTf,
                               unsigned short* __restrict__ hfinp){
  int idx = blockIdx.x * blockDim.x + threadIdx.x;  // 3*32*1024 exact
  int h = idx & 1023;
  int b = (idx >> 10) & 31;
  int v = idx >> 15;
  float val = h0[((size_t)b * L_ + v) * 1024 + h];
  HTb[idx] = f2bf(val);
  HTf[idx] = val;                              // ring slot v&7 == v for v<3
  hfinp[(size_t)v * PLANE + afrag_off(b, h)] = f2bf(val);
}

// ---------------- cheap monotonic tree barrier (R1-proven) ------------------
// bar layout (uints): sub[x] at x*16 (x=0..7), top at 128, gen at 144.
// No cache maintenance: all cross-block data moves via agent-scope loads/
// stores coherent at the IC. __syncthreads drains vmcnt before arrival.
__device__ __forceinline__ void tree_barrier(unsigned* bar, unsigned target){
  __syncthreads();   // drains vmcnt for all waves of this block
  if (threadIdx.x == 0){
    unsigned* sub = bar + (blockIdx.x & 7) * 16;
    unsigned* top = bar + 128;
    unsigned* gen = bar + 144;
    unsigned old = __hip_atomic_fetch_add(sub, 1u, __ATOMIC_RELAXED, __HIP_MEMORY_SCOPE_AGENT);
    if (old == target * (NBLK / 8) - 1u){
      unsigned t2 = __hip_atomic_fetch_add(top, 1u, __ATOMIC_RELAXED, __HIP_MEMORY_SCOPE_AGENT);
      if (t2 == target * 8u - 1u)
        __hip_atomic_store(gen, target, __ATOMIC_RELAXED, __HIP_MEMORY_SCOPE_AGENT);
    }
    while (__hip_atomic_load(gen, __ATOMIC_RELAXED, __HIP_MEMORY_SCOPE_AGENT) < target)
      __builtin_amdgcn_s_sleep(1);
  }
  __syncthreads();
}

// ------- pipelined 64-step GEMM producing TWO 16-col tiles ------------------
// A-fragments loaded ONCE (first 32 kb from inp, last 32 from st/rp), applied
// to tile0 weights (LDS ds_read) and tile1 weights (streamed plain 16B loads,
// per-XCD L2-resident read-only). A+W loads share one counted pipeline:
// batch = 8 A + 8 W = 16 vm ops, depth 2 = 32 in flight; waits 16,...,16,0.
// Exits at vmcnt(0). Per-column accumulation order = kb 0..63 (unchanged).
template<bool DCI>
__device__ __forceinline__ void gemm2(const unsigned short* __restrict__ inp,
                                      const unsigned short* __restrict__ st,
                                      const unsigned short* w0,   // LDS tile 0
                                      const unsigned short* __restrict__ w1g,
                                      int mh, int lane, f4& acc0, f4& acc1){
  const unsigned short* pi = inp + mh * 16384 + lane * 8;
  const unsigned short* ps = st  + mh * 16384 + lane * 8;
  const unsigned short* pw = w1g + lane * 8;
  short8 ab[2][8], wb[2][8];
  #pragma unroll
  for (int b = 0; b < 2; ++b){
    #pragma unroll
    for (int j = 0; j < 8; ++j) ab[b][j] = ldA<DCI>(pi + (size_t)(b * 8 + j) * 512);
    #pragma unroll
    for (int j = 0; j < 8; ++j) wb[b][j] = ldA<false>(pw + (size_t)(b * 8 + j) * 512);
  }
  acc0 = f4{0.f, 0.f, 0.f, 0.f};
  acc1 = f4{0.f, 0.f, 0.f, 0.f};
  #pragma unroll
  for (int b = 0; b < 8; ++b){
    short8 wv[8];                              // LDS reads issued before the wait
    #pragma unroll
    for (int j = 0; j < 8; ++j)
      wv[j] = *(const short8*)(w0 + (size_t)((b * 8 + j) * 64 + lane) * 8);
    if (b < 7) waitv<16>(); else waitv<0>();
    #pragma unroll
    for (int j = 0; j < 8; ++j)
      acc0 = __builtin_amdgcn_mfma_f32_16x16x32_bf16(ab[b & 1][j], wv[j], acc0, 0, 0, 0);
    #pragma unroll
    for (int j = 0; j < 8; ++j)
      acc1 = __builtin_amdgcn_mfma_f32_16x16x32_bf16(ab[b & 1][j], wb[b & 1][j], acc1, 0, 0, 0);
    if (b < 6){
      const int nb = b + 2;
      #pragma unroll
      for (int j = 0; j < 8; ++j){
        if (nb < 4) ab[b & 1][j] = ldA<DCI>(pi + (size_t)(nb * 8 + j) * 512);
        else        ab[b & 1][j] = ldA<true>(ps + (size_t)((nb - 4) * 8 + j) * 512);
      }
      #pragma unroll
      for (int j = 0; j < 8; ++j)
        wb[b & 1][j] = ldA<false>(pw + (size_t)(nb * 8 + j) * 512);
    }
  }
}

// ---------------- persistent recurrence: fat 2-tile blocks ------------------
// 288 blocks x 128 threads (2 waves: wave = mh = batch half). 64 KB LDS
// (tile 0) -> all blocks resident (capacity 2/CU). Each block owns 32 output
// columns = 2 tiles: tile 0 weights in LDS, tile 1 streamed from L2.
// Blocks 0..191   (A): g = blk>>6, jp = blk&63 -> A-tiles 2jp, 2jp+1 of 128.
//                      jp<32 => z columns, else r columns (same half per block).
// Blocks 192..287 (B): g = (blk-192)>>5, jp = (blk-192)&31 -> B-tiles 2jp, 2jp+1 of 64.
__global__ __launch_bounds__(128) void gru_persist(
    const unsigned short* __restrict__ WAp, const unsigned short* __restrict__ WBp,
    const unsigned short* __restrict__ Xp,
    unsigned short* __restrict__ hL0p, unsigned short* __restrict__ hL1p,
    unsigned short* __restrict__ hfinp,
    unsigned short* __restrict__ HTb, float* __restrict__ HTf,
    float* __restrict__ zbuf, unsigned short* __restrict__ rsp,
    const float* __restrict__ bz, const float* __restrict__ br,
    const float* __restrict__ bg, unsigned* bar)
{
  __shared__ unsigned short ldsw[32768];   // 64 KB: tile-0 weights
  const int blk = blockIdx.x;
  const int lane = threadIdx.x & 63;
  const int mh = threadIdx.x >> 6;
  const int quad = lane >> 4, l15 = lane & 15;

  const bool isA = blk < 192;
  int g, jp;
  const unsigned short *wL, *wS;
  if (isA){ g = blk >> 6; jp = blk & 63;
            wL = WAp + (size_t)(g * 128 + 2 * jp) * 32768;
            wS = WAp + (size_t)(g * 128 + 2 * jp + 1) * 32768; }
  else    { int b2 = blk - 192; g = b2 >> 5; jp = b2 & 31;
            wL = WBp + (size_t)(g * 64 + 2 * jp) * 32768;
            wS = WBp + (size_t)(g * 64 + 2 * jp + 1) * 32768; }

  // bootstrap: tile-0 weights -> LDS (coalesced 16B/lane)
  for (int i = threadIdx.x; i < 4096; i += 128)
    *(short8*)(ldsw + (size_t)i * 8) = *(const short8*)(wL + (size_t)i * 8);
  __syncthreads();

  const int n0 = 2 * jp * 16 + l15;        // tile-0 column; tile 1 = n0+16
  float bias0, bias1;
  if (isA){
    bool isz = jp < 32;
    bias0 = isz ? bz[g * H_ + n0]      : br[g * H_ + n0 - 1024];
    bias1 = isz ? bz[g * H_ + n0 + 16] : br[g * H_ + n0 + 16 - 1024];
  } else {
    bias0 = bg[g * H_ + n0];
    bias1 = bg[g * H_ + n0 + 16];
  }

  unsigned tgt = 1;
  for (int s = -4; s <= 2 * S_ - 1; ++s){
    int u = ((s & 1) ? (s - 1) : s) / 2;   // exact
    int v = u + 2;                          // state index this slot
    bool aphase = !(s & 1);
    if (aphase == isA){
      int t = u + 2 - g;
      if (t >= 0 && t < S_){
        int tm = t & 3;
        const unsigned short* inp = (g == 0) ? Xp + (size_t)t * PLANE
                                  : (g == 1) ? hL0p + (size_t)tm * PLANE
                                             : hL1p + (size_t)tm * PLANE;
        const float* sf = HTf + (size_t)(v & 7) * BH;
        if (isA){
          // ---------------- A work: z or r*s (2 tiles) ----------------
          const unsigned short* st = hfinp + (size_t)(v & 7) * PLANE;
          f4 acc0, acc1;
          if (g == 0) gemm2<false>(inp, st, ldsw, wS, mh, lane, acc0, acc1);
          else        gemm2<true >(inp, st, ldsw, wS, mh, lane, acc0, acc1);
          if (jp < 32){
            float* zb = zbuf + (size_t)(g * 4 + tm) * BH;
            #pragma unroll
            for (int r = 0; r < 4; ++r){
              int b = mh * 16 + quad * 4 + r;
              stf_dc(zb + b * H_ + n0,      sigmoidf_(acc0[r] + bias0));
              stf_dc(zb + b * H_ + n0 + 16, sigmoidf_(acc1[r] + bias1));
            }
          } else {
            unsigned short* rp = rsp + (size_t)(g * 4 + tm) * PLANE;
            int n = n0 - 1024;
            #pragma unroll
            for (int r = 0; r < 4; ++r){
              int b = mh * 16 + quad * 4 + r;
              float sv0 = ldf_dc(sf + b * H_ + n);
              float sv1 = ldf_dc(sf + b * H_ + n + 16);
              stu16_dc(rp + afrag_off(b, n),      f2bf(sigmoidf_(acc0[r] + bias0) * sv0));
              stu16_dc(rp + afrag_off(b, n + 16), f2bf(sigmoidf_(acc1[r] + bias1) * sv1));
            }
          }
        } else {
          // ---------------- B work: h (2 tiles) ----------------
          const unsigned short* rp = rsp + (size_t)(g * 4 + tm) * PLANE;
          f4 acc0, acc1;
          if (g == 0) gemm2<false>(inp, rp, ldsw, wS, mh, lane, acc0, acc1);
          else        gemm2<true >(inp, rp, ldsw, wS, mh, lane, acc0, acc1);
          const float* zb = zbuf + (size_t)(g * 4 + tm) * BH;
          #pragma unroll
          for (int r = 0; r < 4; ++r){
            int b = mh * 16 + quad * 4 + r;
            #pragma unroll
            for (int i = 0; i < 2; ++i){
              int n = n0 + i * 16;
              float a = i ? acc1[r] : acc0[r];
              float bi = i ? bias1 : bias0;
              float gg = tanhf(a + bi);
              float z = ldf_dc(zb + b * H_ + n);
              float sv = ldf_dc(sf + b * H_ + n);
              float h = z * sv + (1.f - z) * gg;
              unsigned short hb = f2bf(h);
              if (g == 2){
                stf_dc(HTf + (size_t)((t + 3) & 7) * BH + b * H_ + n, h);
                HTb[(size_t)(t + 3) * BH + b * H_ + n] = hb;   // read post-kernel only
                stu16_dc(hfinp + (size_t)((t + 3) & 7) * PLANE + afrag_off(b, n), hb);
              } else if (g == 0){
                stu16_dc(hL0p + (size_t)tm * PLANE + afrag_off(b, n), hb);
              } else {
                stu16_dc(hL1p + (size_t)tm * PLANE + afrag_off(b, n), hb);
              }
            }
          }
        }
      }
    }
    tree_barrier(bar, tgt++);
  }
}

// ---------------- epilogue: Y = HT @ Wout + bout ----------------------------
__global__ __launch_bounds__(256) void out_proj_kernel(
    const unsigned short* __restrict__ HTb, const unsigned short* __restrict__ WoutP,
    const float* __restrict__ bout, float* __restrict__ Y){
  int tstep = blockIdx.x >> 2;
  int nblk  = blockIdx.x & 3;
  int wave = threadIdx.x >> 6, lane = threadIdx.x & 63;
  int quad = lane >> 4, l15 = lane & 15;
  const unsigned short* A = HTb + (size_t)(tstep + 3) * BH;
  f4 acc[2][4] = {};
  for (int kk = 0; kk < 32; ++kk){
    int k0 = kk * 32 + quad * 8;
    short8 a0 = *(const short8*)(A + l15 * H_ + k0);
    short8 a1 = *(const short8*)(A + (l15 + 16) * H_ + k0);
    #pragma unroll
    for (int nt = 0; nt < 4; ++nt){
      int tile = nblk * 16 + wave * 4 + nt;
      short8 bv = ((const short8*)WoutP)[((size_t)tile * 32 + kk) * 64 + lane];
      acc[0][nt] = __builtin_amdgcn_mfma_f32_16x16x32_bf16(a0, bv, acc[0][nt], 0, 0, 0);
      acc[1][nt] = __builtin_amdgcn_mfma_f32_16x16x32_bf16(a1, bv, acc[1][nt], 0, 0, 0);
    }
  }
  #pragma unroll
  for (int mt = 0; mt < 2; ++mt)
    #pragma unroll
    for (int nt = 0; nt < 4; ++nt)
      #pragma unroll
      for (int r = 0; r < 4; ++r){
        int b = mt * 16 + quad * 4 + r;
        int n = nblk * 256 + wave * 64 + nt * 16 + l15;
        Y[(size_t)b * (S_ * 1024) + (size_t)tstep * 1024 + n] = acc[mt][nt][r] + bout[n];
      }
}

__global__ void copy_hidden_kernel(const float* __restrict__ HTf, float* __restrict__ out2){
  int idx = blockIdx.x * blockDim.x + threadIdx.x;  // 3*32*1024 exact
  int h = idx & 1023;
  int b = (idx >> 10) & 31;
  int v = idx >> 15;
  out2[((size_t)b * L_ + v) * 1024 + h] = HTf[(size_t)((S_ + v) & 7) * BH + b * H_ + h];
}

// ---------------------------------------------------------------------------
extern "C" void kernel_launch(void* const* d_in, const int* in_sizes, int n_in,
                              void* d_out, int out_size, void* d_ws, size_t ws_size,
                              hipStream_t stream){
  (void)in_sizes; (void)n_in; (void)out_size;
  const float* x    = (const float*)d_in[0];
  const float* h0   = (const float*)d_in[1];
  const float* Wx   = (const float*)d_in[2];
  const float* Wz   = (const float*)d_in[3];
  const float* bz   = (const float*)d_in[4];
  const float* Wr   = (const float*)d_in[5];
  const float* Wh   = (const float*)d_in[6];
  const float* br   = (const float*)d_in[7];
  const float* Wg   = (const float*)d_in[8];
  const float* Whg  = (const float*)d_in[9];
  const float* bg   = (const float*)d_in[10];
  const float* Wout = (const float*)d_in[11];
  const float* bout = (const float*)d_in[12];
  float* out = (float*)d_out;

  char* p = (char*)d_ws;
  unsigned short* WAp   = (unsigned short*)p; p += (size_t)384 * 32768 * 2;
  unsigned short* WBp   = (unsigned short*)p; p += (size_t)192 * 32768 * 2;
  unsigned short* WoutP = (unsigned short*)p; p += (size_t)64 * 32 * 64 * 8 * 2;
  unsigned short* Xp    = (unsigned short*)p; p += (size_t)S_ * PLANE * 2;
  unsigned short* HTb   = (unsigned short*)p; p += (size_t)(S_ + 3) * BH * 2;
  float*          HTf   = (float*)p;          p += (size_t)8 * BH * 4;
  unsigned short* hfinp = (unsigned short*)p; p += (size_t)8 * PLANE * 2;
  unsigned short* hL0p  = (unsigned short*)p; p += (size_t)4 * PLANE * 2;
  unsigned short* hL1p  = (unsigned short*)p; p += (size_t)4 * PLANE * 2;
  unsigned short* rsp   = (unsigned short*)p; p += (size_t)12 * PLANE * 2;
  float*          zbuf  = (float*)p;          p += (size_t)12 * BH * 4;
  unsigned*       bar   = (unsigned*)p;       p += 4096;
  if ((size_t)(p - (char*)d_ws) > ws_size) return;

  hipMemsetAsync(bar, 0, 4096, stream);
  prep_WA_packed  <<<6144, 256, 0, stream>>>(Wx, Wz, Wr, Wh, WAp);
  prep_WB_packed  <<<3072, 256, 0, stream>>>(Wg, Whg, WBp);
  prep_Wout_packed<<< 512, 256, 0, stream>>>(Wout, WoutP);
  prep_X_packed   <<<65536, 256, 0, stream>>>(x, Xp);
  prep_H0_kernel  <<<  384, 256, 0, stream>>>(h0, HTb, HTf, hfinp);

  gru_persist<<<NBLK, 128, 0, stream>>>(WAp, WBp, Xp, hL0p, hL1p, hfinp,
                                        HTb, HTf, zbuf, rsp, bz, br, bg, bar);

  out_proj_kernel   <<<2048, 256, 0, stream>>>(HTb, WoutP, bout, out);
  copy_hidden_kernel<<< 384, 256, 0, stream>>>(HTf, out + (size_t)B_ * S_ * 1024);
}